// Round 14
// baseline (43.992 us; speedup 1.0000x reference)
//
#include <hip/hip_runtime.h>

typedef _Float16 f16x8 __attribute__((ext_vector_type(8)));
typedef _Float16 f16x4 __attribute__((ext_vector_type(4)));
typedef float    f32x4 __attribute__((ext_vector_type(4)));
typedef unsigned int u32x4 __attribute__((ext_vector_type(4)));

constexpr int NTOK   = 1568;       // T*H*W = 8*14*14
constexpr int NHEADS = 8;
constexpr int NCH    = 512;
constexpr int NC32   = 52;         // 32-token chunks, padded to 1664 tokens
constexpr float SK   = 0.15014030f; // 0.125*sqrt(log2 e): (q*SK)·(k*SK) = s*log2e/64 -> p = exp2(.)
constexpr size_t IMG_BH = (size_t)NC32 * 4096;   // 212992 B per (bh) per image

// ---- pre-pass: build fragment-major K and V images (every frag = contiguous 1KB, lane*16) ----
// K frag (c16 = tok/16, ks): slot(l15,grp,j) = x[tok=c16*16+l15][d=ks*32+8grp+j] * SK
// V frag (c32 = tok/32, db): slot(l15,grp,j) = x[tok=c32*32+16*(j>>2)+4grp+(j&3)][d=db*16+l15]
__global__ __launch_bounds__(256)
void prep_kernel(const float* __restrict__ x, char* __restrict__ Kimg, char* __restrict__ Vimg)
{
    const int bh = blockIdx.x, c32 = blockIdx.y;
    const int b = bh >> 3, h = bh & 7;
    const int t = threadIdx.x;
    const int f = t >> 6, l = t & 63, l15 = l & 15, grp = l >> 4;

    char* Kg = Kimg + (size_t)bh * IMG_BH + (size_t)(c32 * 4 + f) * 1024 + l * 16;
    char* Vg = Vimg + (size_t)bh * IMG_BH + (size_t)(c32 * 4 + f) * 1024 + l * 16;

    const int n0 = c32 * 32;
    if (n0 >= NTOK) {                       // pure padding chunk
        f16x8 z;
#pragma unroll
        for (int j = 0; j < 8; ++j) z[j] = (_Float16)0.f;
        *(f16x8*)Kg = z; *(f16x8*)Vg = z;
        return;
    }

    __shared__ _Float16 kbuf[32][72];       // [tok][d], scaled
    __shared__ _Float16 vbuf[64][40];       // [d][tok]

    const int tok = t & 31, dhi = t >> 5;   // coalesced: 8 x 128B segments per pass
#pragma unroll
    for (int p = 0; p < 8; ++p) {
        const int d = 8 * p + dhi;
        const float v = x[((size_t)b * NCH + d * NHEADS + h) * NTOK + n0 + tok];
        kbuf[tok][d] = (_Float16)(v * SK);
        vbuf[d][tok] = (_Float16)v;
    }
    __syncthreads();

    // K frag f: cb = f>>1 (16-tok half), ks = f&1
    *(f16x8*)Kg = *(const f16x8*)&kbuf[(f >> 1) * 16 + l15][(f & 1) * 32 + grp * 8];
    // V frag db = f: token quads {4grp..+3} and {16+4grp..+3}
    f16x4 va = *(const f16x4*)&vbuf[f * 16 + l15][4 * grp];
    f16x4 vb = *(const f16x4*)&vbuf[f * 16 + l15][16 + 4 * grp];
    f16x8 vv;
#pragma unroll
    for (int j = 0; j < 4; ++j) { vv[j] = va[j]; vv[4 + j] = vb[j]; }
    *(f16x8*)Vg = vv;
}

// pack 8 exp2(s) values into one P fragment — pure register ops, no union/memory
static __device__ __forceinline__ f16x8 make_bp(f32x4 sA, f32x4 sB)
{
    u32x4 w;
    w[0] = __builtin_bit_cast(unsigned int,
        __builtin_amdgcn_cvt_pkrtz(__builtin_amdgcn_exp2f(sA[0]), __builtin_amdgcn_exp2f(sA[1])));
    w[1] = __builtin_bit_cast(unsigned int,
        __builtin_amdgcn_cvt_pkrtz(__builtin_amdgcn_exp2f(sA[2]), __builtin_amdgcn_exp2f(sA[3])));
    w[2] = __builtin_bit_cast(unsigned int,
        __builtin_amdgcn_cvt_pkrtz(__builtin_amdgcn_exp2f(sB[0]), __builtin_amdgcn_exp2f(sB[1])));
    w[3] = __builtin_bit_cast(unsigned int,
        __builtin_amdgcn_cvt_pkrtz(__builtin_amdgcn_exp2f(sB[2]), __builtin_amdgcn_exp2f(sB[3])));
    return __builtin_bit_cast(f16x8, w);
}

// load one chunk's 4 fragment blocks (4KB, 16B/lane each) into named registers
static __device__ __forceinline__ void load4(const char* base,
                                             f16x8& f0, f16x8& f1, f16x8& f2, f16x8& f3)
{
    f0 = *(const f16x8*)(base);
    f1 = *(const f16x8*)(base + 1024);
    f2 = *(const f16x8*)(base + 2048);
    f3 = *(const f16x8*)(base + 3072);
}

// full per-chunk compute: QK S^T (2 q-subgroups) -> exp/pack -> denominator + PV
static __device__ __forceinline__ void chunk_compute(
    const f16x8& k0, const f16x8& k1, const f16x8& k2, const f16x8& k3,
    const f16x8& v0, const f16x8& v1, const f16x8& v2, const f16x8& v3,
    const f16x8 (&aq)[2][2], const f16x8& ones,
    f32x4 (&oacc)[2][4], f32x4 (&lacc)[2])
{
    const f32x4 z4 = {0.f, 0.f, 0.f, 0.f};
#pragma unroll
    for (int sub = 0; sub < 2; ++sub) {
        f32x4 sA = __builtin_amdgcn_mfma_f32_16x16x32_f16(k0, aq[sub][0], z4, 0, 0, 0);
        sA = __builtin_amdgcn_mfma_f32_16x16x32_f16(k1, aq[sub][1], sA, 0, 0, 0);
        f32x4 sB = __builtin_amdgcn_mfma_f32_16x16x32_f16(k2, aq[sub][0], z4, 0, 0, 0);
        sB = __builtin_amdgcn_mfma_f32_16x16x32_f16(k3, aq[sub][1], sB, 0, 0, 0);
        const f16x8 bp = make_bp(sA, sB);   // slot j = token 16*(j>>2)+4grp+(j&3)
        lacc[sub]   = __builtin_amdgcn_mfma_f32_16x16x32_f16(ones, bp, lacc[sub], 0, 0, 0);
        oacc[sub][0] = __builtin_amdgcn_mfma_f32_16x16x32_f16(v0, bp, oacc[sub][0], 0, 0, 0);
        oacc[sub][1] = __builtin_amdgcn_mfma_f32_16x16x32_f16(v1, bp, oacc[sub][1], 0, 0, 0);
        oacc[sub][2] = __builtin_amdgcn_mfma_f32_16x16x32_f16(v2, bp, oacc[sub][2], 0, 0, 0);
        oacc[sub][3] = __builtin_amdgcn_mfma_f32_16x16x32_f16(v3, bp, oacc[sub][3], 0, 0, 0);
    }
}

// combine helpers: statically-indexed register arrays by reference (inlined -> stays in VGPRs)
static __device__ __forceinline__ void dump_part(float (*row)[35], int lane,
                                                 const f32x4 (&oacc)[2][4], const f32x4 (&lacc)[2])
{
#pragma unroll
    for (int s = 0; s < 2; ++s) {
#pragma unroll
        for (int db = 0; db < 4; ++db)
#pragma unroll
            for (int q = 0; q < 4; ++q) row[lane][s * 16 + db * 4 + q] = oacc[s][db][q];
        row[lane][32 + s] = lacc[s][0];
    }
}
static __device__ __forceinline__ void add_part(const float (*row)[35], int lane,
                                                f32x4 (&oacc)[2][4], f32x4 (&lacc)[2])
{
#pragma unroll
    for (int s = 0; s < 2; ++s) {
#pragma unroll
        for (int db = 0; db < 4; ++db)
#pragma unroll
            for (int q = 0; q < 4; ++q) oacc[s][db][q] += row[lane][s * 16 + db * 4 + q];
        lacc[s][0] += row[lane][32 + s];
    }
}

// ---- main attention: QBLK=32, 4-wave k-split, register DOUBLE-BUFFER (A/B ping-pong) ----
// Loads for chunk i+1 issue at top of iteration i into the idle buffer -> full-iteration
// (~450 cyc) prefetch distance, no reuse hazard. Padded image makes the +1 prefetch safe.
__global__ __launch_bounds__(256, 3)
void attn_fwd(const char* __restrict__ Kimg, const char* __restrict__ Vimg,
              float* __restrict__ out)
{
    // XCD-aware bijective remap (1568 = 8*196): 4 bh per XCD -> both images L2-resident
    const int orig = blockIdx.x;
    const int wgid = (orig & 7) * 196 + (orig >> 3);
    const int qt = wgid % 49, bh = wgid / 49;       // qt: 32-row q-tile, 49*32 = 1568 exactly
    const int b = bh >> 3, head = bh & 7;
    const int t = threadIdx.x, kw = t >> 6, lane = t & 63;
    const int l15 = lane & 15, grp = lane >> 4;

    const char* Kb = Kimg + (size_t)bh * IMG_BH;
    const char* Vb = Vimg + (size_t)bh * IMG_BH;

    // Q fragments: B operand (col = l15 = q-row), from the padded K image (scale baked in)
    f16x8 aq[2][2];
#pragma unroll
    for (int sub = 0; sub < 2; ++sub)
#pragma unroll
        for (int ks = 0; ks < 2; ++ks)
            aq[sub][ks] = *(const f16x8*)(Kb + (size_t)((qt * 2 + sub) * 2 + ks) * 1024 + lane * 16);

    f16x8 ones;
#pragma unroll
    for (int j = 0; j < 8; ++j) ones[j] = (_Float16)1.f;

    f32x4 oacc[2][4];
    f32x4 lacc[2];
#pragma unroll
    for (int s = 0; s < 2; ++s) {
        lacc[s] = f32x4{0.f, 0.f, 0.f, 0.f};
#pragma unroll
        for (int db = 0; db < 4; ++db) oacc[s][db] = f32x4{0.f, 0.f, 0.f, 0.f};
    }

    // 49 valid chunks split 13/12/12/12 across the 4 kw waves
    const int start = (kw == 0) ? 0 : 13 + (kw - 1) * 12;
    const int nc    = (kw == 0) ? 13 : 12;

    // A/B register buffers (named, statically selected -> no copies, no scratch)
    f16x8 ak0, ak1, ak2, ak3, av0, av1, av2, av3;
    f16x8 bk0, bk1, bk2, bk3, bv0, bv1, bv2, bv3;

    load4(Kb + (size_t)start * 4096 + lane * 16, ak0, ak1, ak2, ak3);
    load4(Vb + (size_t)start * 4096 + lane * 16, av0, av1, av2, av3);

    int i = 0;
    for (; i + 2 <= nc; i += 2) {
        // prefetch chunk i+1 into B while computing A (chunk i)
        load4(Kb + (size_t)(start + i + 1) * 4096 + lane * 16, bk0, bk1, bk2, bk3);
        load4(Vb + (size_t)(start + i + 1) * 4096 + lane * 16, bv0, bv1, bv2, bv3);
        chunk_compute(ak0, ak1, ak2, ak3, av0, av1, av2, av3, aq, ones, oacc, lacc);
        // prefetch chunk i+2 into A while computing B (chunk i+1); start+nc <= 49 < 52: in padded image
        load4(Kb + (size_t)(start + i + 2) * 4096 + lane * 16, ak0, ak1, ak2, ak3);
        load4(Vb + (size_t)(start + i + 2) * 4096 + lane * 16, av0, av1, av2, av3);
        chunk_compute(bk0, bk1, bk2, bk3, bv0, bv1, bv2, bv3, aq, ones, oacc, lacc);
    }
    if (i < nc)   // odd tail (kw==0 only, chunk 12 already resident in A)
        chunk_compute(ak0, ak1, ak2, ak3, av0, av1, av2, av3, aq, ones, oacc, lacc);

    // ---- combine the 4 kw waves (sequential rounds, one small LDS buffer) ----
    __shared__ float comb[64][35];          // stride 35 (odd): worst 2-way banks = free
    for (int r = 1; r < 4; ++r) {
        if (kw == r) dump_part(comb, lane, oacc, lacc);
        __syncthreads();
        if (kw == 0) add_part(comb, lane, oacc, lacc);
        __syncthreads();
    }

    if (kw == 0) {
        // lacc[s][0] is the full denominator for column q = l15 (MFMA reduced all k in-instruction)
#pragma unroll
        for (int sub = 0; sub < 2; ++sub) {
            const int qrow = qt * 32 + sub * 16 + l15;      // always < 1568
            const float inv = 1.0f / lacc[sub][0];
#pragma unroll
            for (int db = 0; db < 4; ++db)
#pragma unroll
                for (int q = 0; q < 4; ++q) {
                    const int d = db * 16 + 4 * grp + q;    // O^T: row=d, col=q
                    out[((size_t)b * NCH + (size_t)d * NHEADS + head) * NTOK + qrow] = oacc[sub][db][q] * inv;
                }
        }
    }
}

extern "C" void kernel_launch(void* const* d_in, const int* in_sizes, int n_in,
                              void* d_out, int out_size, void* d_ws, size_t ws_size,
                              hipStream_t stream)
{
    const float* x = (const float*)d_in[0];
    float* out     = (float*)d_out;

    char* Kimg = (char*)d_ws;                       // 32 * 208KB = 6.8 MB
    char* Vimg = (char*)d_ws + 32 * IMG_BH;         // + 6.8 MB

    dim3 pgrid(32, NC32);                           // 32 bh x 52 chunks
    prep_kernel<<<pgrid, 256, 0, stream>>>(x, Kimg, Vimg);

    attn_fwd<<<1568, 256, 0, stream>>>(Kimg, Vimg, out);   // 49 q-tiles x 32 bh, XCD-remapped
}